// Round 3
// baseline (299.509 us; speedup 1.0000x reference)
//
#include <hip/hip_runtime.h>
#include <math.h>

namespace {

constexpr int Bn = 16, Tn = 512, Dn = 768, Sn = 4, Hn = 48, On = 48;
constexpr int Mn = Bn * Tn;          // 8192 (b,t) rows
constexpr int Gn = Sn * Hn;          // 192 (s,h) groups
constexpr int Nn = Gn * On;          // 9216 flat N (= flat W rows)
constexpr float EMISS_W = 0.5f;

// workspace layout (float offsets), then bf16 regions ~27 MB
constexpr size_t OFF_LP   = 0;
constexpr size_t OFF_LT   = 64;
constexpr size_t OFF_PT   = OFF_LT + Hn*Hn;
constexpr size_t OFF_EM   = OFF_PT + Hn*Hn;
constexpr size_t OFF_LEPP = OFF_EM + (size_t)Sn*Hn*On;   // [m][g] g = s*48+h (log partials)
constexpr size_t OFF_LA   = OFF_LEPP + (size_t)Mn*Gn;    // alpha probs (per-t scale)
constexpr size_t OFF_LB   = OFF_LA + (size_t)Mn*Hn;      // beta probs (per-t scale)
constexpr size_t OFF_RED  = OFF_LB + (size_t)Mn*Hn;      // per-(b,t) partials [8192]
constexpr size_t FLOATS_END = OFF_RED + (size_t)Mn;

typedef __attribute__((ext_vector_type(8))) short short8;
typedef __attribute__((ext_vector_type(4))) float f32x4;

__device__ inline float waveSum(float v){
#pragma unroll
  for (int o = 32; o; o >>= 1) v += __shfl_xor(v, o);
  return v;
}

__device__ inline unsigned short f2bf(float f){
  unsigned int u = __float_as_uint(f);
  u += 0x7FFFu + ((u >> 16) & 1u);   // round-to-nearest-even
  return (unsigned short)(u >> 16);
}

__device__ inline void gload_lds16(const void* g, void* l){
  __builtin_amdgcn_global_load_lds(
      (const __attribute__((address_space(1))) void*)g,
      (__attribute__((address_space(3))) void*)l, 16, 0, 0);
}

// -------- conversion (all blocks but last) + param preprocessing (last block) --
__global__ void convprep_kernel(const float* __restrict__ srcA, unsigned short* __restrict__ dstA,
                                int n4a,
                                const float* __restrict__ srcB, unsigned short* __restrict__ dstB,
                                int n4b,
                                const float* __restrict__ sp, const float* __restrict__ ut,
                                const float* __restrict__ ue, float* __restrict__ ws,
                                int nconv){
  const int tid = threadIdx.x;
  if ((int)blockIdx.x == nconv){
    // ---- prep ----
    float m = -INFINITY;
    for (int h = 0; h < Hn; ++h) m = fmaxf(m, sp[h]);
    float s = 0.f;
    for (int h = 0; h < Hn; ++h) s += __expf(sp[h] - m);
    float lse = m + __logf(s);
    if (tid < Hn) ws[OFF_LP + tid] = sp[tid] - lse;
    if (tid < Hn){
      const float* row = ut + tid * Hn;
      float mm = -INFINITY;
      for (int j = 0; j < Hn; ++j) mm = fmaxf(mm, row[j]);
      float ss = 0.f;
      for (int j = 0; j < Hn; ++j) ss += __expf(row[j] - mm);
      float l = mm + __logf(ss);
      for (int j = 0; j < Hn; ++j){
        float v = row[j] - l;
        ws[OFF_LT + tid*Hn + j] = v;
        ws[OFF_PT + tid*Hn + j] = __expf(v);
      }
    }
    for (int r = tid; r < Sn*Hn; r += blockDim.x){
      const float* row = ue + (size_t)r * On;
      float mm = -INFINITY;
      for (int o = 0; o < On; ++o) mm = fmaxf(mm, row[o]);
      float ss = 0.f;
      for (int o = 0; o < On; ++o) ss += __expf(row[o] - mm);
      float inv = 1.f/ss;
      for (int o = 0; o < On; ++o) ws[OFF_EM + (size_t)r*On + o] = __expf(row[o]-mm)*inv;
    }
    return;
  }
  // ---- conv ----
  int i = blockIdx.x * blockDim.x + tid;
  const float* s2; unsigned short* d; int k;
  if (i < n4a){ s2 = srcA; d = dstA; k = i; }
  else { k = i - n4a; if (k >= n4b) return; s2 = srcB; d = dstB; }
  float4 v = ((const float4*)s2)[k];
  ushort4 r;
  r.x = f2bf(v.x); r.y = f2bf(v.y); r.z = f2bf(v.z); r.w = f2bf(v.w);
  ((ushort4*)d)[k] = r;
}

// ---------------- bf16 MFMA GEMM + fused softmax/mix/obs-dot epilogue ----------
// R12: 256x192 tile, 8 waves, BK=64, FULL double buffer, 4 phases/K-tile
// (kk-split): each phase {3-7 ds_reads, 2-3 stage issues, s_barrier,
// lgkmcnt(0), setprio MFMA x12, s_barrier}. Reads issued pre-barrier are
// serviced during barrier-wait; next-phase reads overlap prior MFMA tails
// (m201 overlap structure). All 7 stages for t+1 issued by P3; single
// vmcnt(0) per tile at P4 end (>=2 phases after last issue; slab swizzle
// keeps >90% L2 hits so latency ~200-300cy is covered). XCD slab swizzle
// from R11 kept (FETCH 110MB verified).
constexpr int BM = 256, BN = 192, BK = 64;
constexpr int NKT = Dn / BK;         // 12 K-tiles
// LDS byte map: A[2] @ 0 (2x32KB), B[2] @ 65536 (2x24KB), end 114688.

#define GEMM_BAR()  asm volatile("s_barrier" ::: "memory")
#define GEMM_LGKM() asm volatile("s_waitcnt lgkmcnt(0)" ::: "memory")

__global__ __launch_bounds__(512, 2) void gemm_lep_kernel(
    const unsigned short* __restrict__ embB, const unsigned short* __restrict__ WB,
    const float* __restrict__ bm, const float* __restrict__ obs,
    float* __restrict__ ws){
  __shared__ __align__(16) char smem[114688];   // staging; aliased by C-park
  __shared__ float bias_s[192], em_s[192];
  const int tid = threadIdx.x, lane = tid & 63, w = tid >> 6;
  // XCD slab swizzle (bid%8 = XCD heuristic). 1536 blocks, 1536 % 8 == 0.
  const int bid = blockIdx.y * (Mn/BM) + blockIdx.x;
  const int xcd = bid & 7, j_loc = bid >> 3;     // j_loc in [0,192)
  const int xm = xcd & 3, xn = xcd >> 2;         // m-quarter, N-half
  const int mloc = j_loc & 7, nloc = j_loc >> 3; // inner m, outer n
  const int m0 = (xm*8 + mloc) * BM;             // m-tile 0..31
  const int by = xn*24 + nloc;                   // N-panel 0..47
  const int N0 = by * BN;
  if (tid < 192){
    bias_s[tid] = bm[N0 + tid];
    em_s[tid]   = ws[OFF_EM + N0 + tid];
  }
  const int wm = w & 1, wn = w >> 1;           // 2 x 4 wave grid
  const int lm = lane & 15, q = lane >> 4;
  const int key = lm & 7;
  const int srow = lane >> 3, spc = lane & 7;
  const int aoff0 = (q ^ key) << 4;            // kk=0 chunk byte offset
  const int aoff1 = ((4 + q) ^ key) << 4;      // kk=1

  f32x4 acc[8][3];
#pragma unroll
  for (int i = 0; i < 8; ++i)
#pragma unroll
    for (int j = 0; j < 3; ++j) acc[i][j] = (f32x4){0.f,0.f,0.f,0.f};

  auto stageA2 = [&](int kt, int rb){          // stages A rows [rb+w*8, +8)
    const int r0  = rb + w*8;
    const int row = r0 + srow;
    const int lc  = spc ^ (row & 7);
    gload_lds16(embB + (size_t)(m0+row)*Dn + kt*BK + lc*8,
                smem + ((kt & 1) << 15) + r0*128);
  };
  auto stageB = [&](int kt, int i){            // i = 0..2, rows (w*3+i)*8..
    const int idx = w*3 + i;
    const int row = idx*8 + srow;
    const int lc  = spc ^ (row & 7);
    gload_lds16(WB + (size_t)(N0+row)*Dn + kt*BK + lc*8,
                smem + 65536 + (kt & 1)*24576 + idx*1024);
  };

  // prologue: stage K-tile 0 (7 loads), wait, barrier
  stageA2(0,0); stageA2(0,64); stageA2(0,128); stageA2(0,192);
  stageB(0,0);  stageB(0,1);   stageB(0,2);
  asm volatile("s_waitcnt vmcnt(0)" ::: "memory");
  GEMM_BAR();

  for (int kt = 0; kt < NKT; ++kt){
    const char* Ab = smem + ((kt & 1) << 15);
    const char* Bb = smem + 65536 + (kt & 1)*24576;
    const int pf = kt + 1;
    const bool dopf = pf < NKT;
    short8 af[4], bf[3];

    // ---- P1: kk0, i0-3  (reads 3B + 4A; stage 2) ----
#pragma unroll
    for (int j = 0; j < 3; ++j)
      bf[j] = *(const short8*)(Bb + (wn*48 + j*16 + lm)*128 + aoff0);
#pragma unroll
    for (int i = 0; i < 4; ++i)
      af[i] = *(const short8*)(Ab + (wm*128 + i*16 + lm)*128 + aoff0);
    if (dopf){ stageA2(pf, 0); stageA2(pf, 64); }
    GEMM_BAR();
    GEMM_LGKM();
    __builtin_amdgcn_s_setprio(1);
#pragma unroll
    for (int i = 0; i < 4; ++i)
#pragma unroll
      for (int j = 0; j < 3; ++j)
        acc[i][j] = __builtin_amdgcn_mfma_f32_16x16x32_bf16(af[i], bf[j], acc[i][j], 0, 0, 0);
    __builtin_amdgcn_s_setprio(0);
    GEMM_BAR();

    // ---- P2: kk0, i4-7  (reads 4A; stage 3) ----
#pragma unroll
    for (int i = 0; i < 4; ++i)
      af[i] = *(const short8*)(Ab + (wm*128 + (4+i)*16 + lm)*128 + aoff0);
    if (dopf){ stageA2(pf, 128); stageA2(pf, 192); stageB(pf, 0); }
    GEMM_BAR();
    GEMM_LGKM();
    __builtin_amdgcn_s_setprio(1);
#pragma unroll
    for (int i = 0; i < 4; ++i)
#pragma unroll
      for (int j = 0; j < 3; ++j)
        acc[4+i][j] = __builtin_amdgcn_mfma_f32_16x16x32_bf16(af[i], bf[j], acc[4+i][j], 0, 0, 0);
    __builtin_amdgcn_s_setprio(0);
    GEMM_BAR();

    // ---- P3: kk1, i0-3  (reads 3B + 4A; stage 2) ----
#pragma unroll
    for (int j = 0; j < 3; ++j)
      bf[j] = *(const short8*)(Bb + (wn*48 + j*16 + lm)*128 + aoff1);
#pragma unroll
    for (int i = 0; i < 4; ++i)
      af[i] = *(const short8*)(Ab + (wm*128 + i*16 + lm)*128 + aoff1);
    if (dopf){ stageB(pf, 1); stageB(pf, 2); }
    GEMM_BAR();
    GEMM_LGKM();
    __builtin_amdgcn_s_setprio(1);
#pragma unroll
    for (int i = 0; i < 4; ++i)
#pragma unroll
      for (int j = 0; j < 3; ++j)
        acc[i][j] = __builtin_amdgcn_mfma_f32_16x16x32_bf16(af[i], bf[j], acc[i][j], 0, 0, 0);
    __builtin_amdgcn_s_setprio(0);
    GEMM_BAR();

    // ---- P4: kk1, i4-7  (reads 4A; end-of-tile vmcnt(0)) ----
#pragma unroll
    for (int i = 0; i < 4; ++i)
      af[i] = *(const short8*)(Ab + (wm*128 + (4+i)*16 + lm)*128 + aoff1);
    GEMM_BAR();
    GEMM_LGKM();
    __builtin_amdgcn_s_setprio(1);
#pragma unroll
    for (int i = 0; i < 4; ++i)
#pragma unroll
      for (int j = 0; j < 3; ++j)
        acc[4+i][j] = __builtin_amdgcn_mfma_f32_16x16x32_bf16(af[i], bf[j], acc[4+i][j], 0, 0, 0);
    __builtin_amdgcn_s_setprio(0);
    asm volatile("s_waitcnt vmcnt(0)" ::: "memory");   // tile kt+1 landed
    GEMM_BAR();
  }

  // ---- epilogue: park C over staging in 2 halves (stride 193), fused
  //      softmax / mix / obs-dot / log. 512 threads = 128 rows x 4 groups.
  float* Cp = (float*)smem;
#pragma unroll
  for (int h = 0; h < 2; ++h){
    if (h) __syncthreads();
#pragma unroll
    for (int i = 0; i < 4; ++i)
#pragma unroll
      for (int j = 0; j < 3; ++j){
        const int col = wn*48 + j*16 + lm;
#pragma unroll
        for (int r = 0; r < 4; ++r){
          const int rowl = wm*64 + i*16 + q*4 + r;
          Cp[rowl*193 + col] = acc[h*4+i][j][r];
        }
      }
    __syncthreads();
    {
      const int rowl = tid >> 2, grp = tid & 3;
      const int trow = (rowl >> 6)*128 + h*64 + (rowl & 63);
      const int m = m0 + trow;
      const int g = by*4 + grp;
      const int s2 = g / Hn;                   // constant per block
      const float* crow = Cp + rowl*193 + grp*48;
      const float* ob   = obs + ((size_t)m*Sn + s2)*On;
      const float* bi   = bias_s + grp*48;
      const float* em   = em_s + grp*48;
      float Z = 0.f, pd = 0.f, eo = 0.f;
#pragma unroll
      for (int o = 0; o < On; ++o){
        float e = __expf(crow[o] + bi[o]);
        float obv = ob[o];
        Z += e;
        pd = fmaf(e, obv, pd);
        eo = fmaf(em[o], obv, eo);
      }
      ws[OFF_LEPP + (size_t)m*Gn + g] = __logf((1.f-EMISS_W)*eo + EMISS_W*(pd/Z));
    }
  }
}

// ---------------- forward/backward recursions: chunked with warm-up ----------
// Serial depth 40 (FBW warm-up + FBL chunk). Stages exp(sum of 4 lep
// partials) straight from OFF_LEPP (lep_reduce kernel deleted).
constexpr int FBW = 24;   // warm-up steps
constexpr int FBL = 16;   // chunk length

__global__ __launch_bounds__(64) void fb_kernel(float* __restrict__ ws){
  __shared__ __align__(16) float ldsE[(FBW+FBL)*48];   // exp(lep) window
  __shared__ __align__(16) float ring[2][64];
  const int lane = threadIdx.x;
  const int c    = blockIdx.x;
  const int b    = blockIdx.y;
  const bool fwd = blockIdx.z == 0;
  const bool act = lane < Hn;
  const int t0 = c*FBL, te = t0 + FBL - 1;

  float pt[Hn];
#pragma unroll
  for (int i = 0; i < Hn; ++i)
    pt[i] = act ? (fwd ? ws[OFF_PT + i*Hn + lane] : ws[OFF_PT + lane*Hn + i]) : 0.f;

  int row_lo, nrows, sA, sZ;
  bool exact;
  if (fwd){
    sA = t0 - FBW;
    exact = (sA < 1);
    row_lo = exact ? 0 : sA;
    if (exact) sA = 1;
    sZ = te;
    nrows = te - row_lo + 1;
  } else {
    int th = te + 1 + FBW;
    exact = (th > Tn - 2);
    sA = exact ? Tn - 2 : th - 1;
    sZ = t0;
    row_lo = t0;
    nrows = sA - t0 + 1;
  }

  // stage exp(lep) = exp(sum of 4 partials) from [m][192] layout
  {
    const float* src = ws + OFF_LEPP + ((size_t)b*Tn + row_lo)*Gn;
    int n4 = nrows * (Hn/4);
    for (int i = lane; i < n4; i += 64){
      int r = i / (Hn/4), h4 = i - r*(Hn/4);
      const float* p = src + (size_t)r*Gn + h4*4;
      float4 a = *(const float4*)(p);
      float4 b2 = *(const float4*)(p + Hn);
      float4 c2 = *(const float4*)(p + 2*Hn);
      float4 d2 = *(const float4*)(p + 3*Hn);
      float4 e;
      e.x = __expf(a.x + b2.x + c2.x + d2.x);
      e.y = __expf(a.y + b2.y + c2.y + d2.y);
      e.z = __expf(a.z + b2.z + c2.z + d2.z);
      e.w = __expf(a.w + b2.w + c2.w + d2.w);
      ((float4*)ldsE)[i] = e;
    }
  }
  __syncthreads();

  if (fwd){
    const size_t laF = OFF_LA + (size_t)b * Tn * Hn;
    float v;
    if (exact){
      v = act ? __expf(ws[OFF_LP + lane]) * ldsE[lane] : 0.f;   // alpha_0
      if (c == 0 && act) ws[laF + lane] = v;
    } else {
      v = act ? 1.f : 0.f;
    }
    if (act) ring[0][lane] = v;
    __syncthreads();
    int cur = 0;
    for (int t = sA; t <= sZ; ++t){
      float S = waveSum(v);
      const float* rp = ring[cur];
      float s0=0.f,s1=0.f,s2=0.f,s3=0.f;
#pragma unroll
      for (int i = 0; i < Hn; i += 4){
        float4 a = *(const float4*)(rp + i);
        s0 = fmaf(a.x, pt[i+0], s0); s1 = fmaf(a.y, pt[i+1], s1);
        s2 = fmaf(a.z, pt[i+2], s2); s3 = fmaf(a.w, pt[i+3], s3);
      }
      float sd = (s0+s1)+(s2+s3);
      float e = act ? ldsE[(t - row_lo)*Hn + lane] : 0.f;
      float vn = act ? e * sd * (1.f/S) : 0.f;
      cur ^= 1;
      if (act) ring[cur][lane] = vn;
      __syncthreads();
      if (act && t >= t0) ws[laF + (size_t)t*Hn + lane] = vn;
      v = vn;
    }
  } else {
    const size_t lbF = OFF_LB + (size_t)b * Tn * Hn;
    float v = act ? 1.f : 0.f;
    if (exact && c == (Tn/FBL - 1) && act) ws[lbF + (size_t)(Tn-1)*Hn + lane] = 1.f;
    int cur = 0;
    for (int t = sA; t >= sZ; --t){
      float e = act ? ldsE[(t - row_lo)*Hn + lane] : 0.f;
      float wv = e * v;
      if (act) ring[cur][lane] = wv;
      float S = waveSum(wv);
      __syncthreads();
      const float* rp = ring[cur];
      float s0=0.f,s1=0.f,s2=0.f,s3=0.f;
#pragma unroll
      for (int j = 0; j < Hn; j += 4){
        float4 a = *(const float4*)(rp + j);
        s0 = fmaf(a.x, pt[j+0], s0); s1 = fmaf(a.y, pt[j+1], s1);
        s2 = fmaf(a.z, pt[j+2], s2); s3 = fmaf(a.w, pt[j+3], s3);
      }
      float vn = act ? ((s0+s1)+(s2+s3)) * (1.f/S) : 0.f;
      cur ^= 1;
      if (act && t <= te) ws[lbF + (size_t)t*Hn + lane] = vn;
      v = vn;
    }
  }
}

// -------- gamma / xi / masked accumulation (prob domain, no atomics) -----------
// One coalesced partial store per block; sum_kernel reduces. (R9's last-block
// counter pattern = 8192 serialized same-address atomics+fences = 165us. Never
// funnel per-block completion through one address on this chip.)
__global__ __launch_bounds__(256) void gamma_xi_kernel(
    const float* __restrict__ ws_c, float* __restrict__ ws,
    const int* __restrict__ seq_len){
  __shared__ float y_s[Hn], lap_s[Hn];
  __shared__ float red[8];
  const int tid = threadIdx.x;
  const int bid = blockIdx.x;
  const int b = bid >> 9, t = bid & (Tn-1);
  const int len = seq_len[b];
  int tb = t + (Tn - len); if (tb >= Tn) tb -= Tn;
  const size_t bt = (size_t)b*Tn + t;
  float lep = 0.f;
  if (tid < Hn){
    const float* lpp = ws_c + OFF_LEPP + bt*Gn + tid;
    lep = lpp[0] + lpp[Hn] + lpp[2*Hn] + lpp[3*Hn];
    float lb  = ws_c[OFF_LB + ((size_t)b*Tn + tb)*Hn + tid];
    y_s[tid] = __expf(lep) * lb;
    if (t >= 1) lap_s[tid] = ws_c[OFF_LA + (bt-1)*Hn + tid];
  }
  float emis_term = 0.f, prior_term = 0.f;
  if (tid < 64){
    int h = (tid < Hn) ? tid : 0;
    float la  = ws_c[OFF_LA + bt*Hn + h];
    float lb  = ws_c[OFF_LB + ((size_t)b*Tn + tb)*Hn + h];
    float lp  = ws_c[OFF_LP + h];
    float wgt = (tid < Hn) ? la*lb : 0.f;
    float Z = waveSum(wgt);
    float inv = 1.f / Z;
    emis_term  = waveSum(wgt * lep) * inv;
    prior_term = waveSum(wgt * lp) * inv;
  }
  __syncthreads();
  float tran_term = 0.f;
  if (t >= 1){
    float se = 0.f, st = 0.f;
#pragma unroll
    for (int k=0;k<9;++k){
      int e = tid + k*256;
      int i = e / Hn, j = e - i*Hn;
      float e2 = ws_c[OFF_PT + e] * lap_s[i] * y_s[j];
      se += e2;
      st = fmaf(e2, ws_c[OFF_LT + e], st);
    }
    se = waveSum(se);
    st = waveSum(st);
    const int wid = tid >> 6;
    if ((tid & 63) == 0){ red[wid] = se; red[4+wid] = st; }
    __syncthreads();
    if (tid == 0){
      float SE = red[0]+red[1]+red[2]+red[3];
      float ST = red[4]+red[5]+red[6]+red[7];
      tran_term = ST / SE;
    }
  }
  if (tid == 0){
    float tot = 0.f;
    if (t < len)            tot += emis_term;
    if (t == 0)             tot += prior_term;
    if (t >= 1 && t < len)  tot += tran_term;
    ws[OFF_RED + bid] = tot;
  }
}

// ---------------- final reduction: 8192 partials -> scalar ---------------------
__global__ __launch_bounds__(256) void sum_kernel(const float* __restrict__ ws,
                                                  float* __restrict__ out){
  __shared__ float red[4];
  const int tid = threadIdx.x;
  float s = 0.f;
  for (int i = tid; i < Mn; i += 256) s += ws[OFF_RED + i];
  s = waveSum(s);
  if ((tid & 63) == 0) red[tid >> 6] = s;
  __syncthreads();
  if (tid == 0) out[0] = (red[0]+red[1]+red[2]+red[3]) * (1.f / Bn);
}

} // namespace

extern "C" void kernel_launch(void* const* d_in, const int* in_sizes, int n_in,
                              void* d_out, int out_size, void* d_ws, size_t ws_size,
                              hipStream_t stream){
  const float* emb = (const float*)d_in[0];
  const float* obs = (const float*)d_in[1];
  const float* sp  = (const float*)d_in[2];
  const float* ut  = (const float*)d_in[3];
  const float* ue  = (const float*)d_in[4];
  const float* Wm  = (const float*)d_in[5];
  const float* bm  = (const float*)d_in[6];
  const int*   sl  = (const int*)d_in[7];
  float* ws  = (float*)d_ws;
  float* out = (float*)d_out;
  (void)in_sizes; (void)n_in; (void)ws_size; (void)out_size;

  unsigned short* embB = (unsigned short*)(ws + FLOATS_END);
  unsigned short* WB   = embB + (size_t)Mn * Dn;

  const int n4a = Mn*Dn/4, n4b = Nn*Dn/4;
  const int nconv = (n4a + n4b + 255)/256;
  convprep_kernel<<<nconv + 1, 256, 0, stream>>>(emb, embB, n4a, Wm, WB, n4b,
                                                 sp, ut, ue, ws, nconv);
  gemm_lep_kernel<<<dim3(Mn/BM, Nn/BN), 512, 0, stream>>>(embB, WB, bm, obs, ws);
  fb_kernel<<<dim3(Tn/FBL, Bn, 2), 64, 0, stream>>>(ws);
  gamma_xi_kernel<<<Bn*Tn, 256, 0, stream>>>(ws, ws, sl);
  sum_kernel<<<1, 256, 0, stream>>>(ws, out);
}

// Round 4
// 294.477 us; speedup vs baseline: 1.0171x; 1.0171x over previous
//
#include <hip/hip_runtime.h>
#include <math.h>

namespace {

constexpr int Bn = 16, Tn = 512, Dn = 768, Sn = 4, Hn = 48, On = 48;
constexpr int Mn = Bn * Tn;          // 8192 (b,t) rows
constexpr int Gn = Sn * Hn;          // 192 (s,h) groups
constexpr int Nn = Gn * On;          // 9216 flat N (= flat W rows)
constexpr float EMISS_W = 0.5f;

// workspace layout (float offsets), then bf16 regions ~27 MB
constexpr size_t OFF_LP   = 0;
constexpr size_t OFF_LT   = 64;
constexpr size_t OFF_PT   = OFF_LT + Hn*Hn;
constexpr size_t OFF_EM   = OFF_PT + Hn*Hn;
constexpr size_t OFF_LEPP = OFF_EM + (size_t)Sn*Hn*On;   // [m][g] g = s*48+h (log partials)
constexpr size_t OFF_LA   = OFF_LEPP + (size_t)Mn*Gn;    // alpha probs (per-t scale)
constexpr size_t OFF_LB   = OFF_LA + (size_t)Mn*Hn;      // beta probs (per-t scale)
constexpr size_t OFF_RED  = OFF_LB + (size_t)Mn*Hn;      // per-(b,t) partials [8192]
constexpr size_t FLOATS_END = OFF_RED + (size_t)Mn;

typedef __attribute__((ext_vector_type(8))) short short8;
typedef __attribute__((ext_vector_type(4))) float f32x4;

__device__ inline float waveSum(float v){
#pragma unroll
  for (int o = 32; o; o >>= 1) v += __shfl_xor(v, o);
  return v;
}

__device__ inline unsigned short f2bf(float f){
  unsigned int u = __float_as_uint(f);
  u += 0x7FFFu + ((u >> 16) & 1u);   // round-to-nearest-even
  return (unsigned short)(u >> 16);
}

__device__ inline void gload_lds16(const void* g, void* l){
  __builtin_amdgcn_global_load_lds(
      (const __attribute__((address_space(1))) void*)g,
      (__attribute__((address_space(3))) void*)l, 16, 0, 0);
}

// -------- conversion (all blocks but last) + param preprocessing (last block) --
__global__ void convprep_kernel(const float* __restrict__ srcA, unsigned short* __restrict__ dstA,
                                int n4a,
                                const float* __restrict__ srcB, unsigned short* __restrict__ dstB,
                                int n4b,
                                const float* __restrict__ sp, const float* __restrict__ ut,
                                const float* __restrict__ ue, float* __restrict__ ws,
                                int nconv){
  const int tid = threadIdx.x;
  if ((int)blockIdx.x == nconv){
    // ---- prep ----
    float m = -INFINITY;
    for (int h = 0; h < Hn; ++h) m = fmaxf(m, sp[h]);
    float s = 0.f;
    for (int h = 0; h < Hn; ++h) s += __expf(sp[h] - m);
    float lse = m + __logf(s);
    if (tid < Hn) ws[OFF_LP + tid] = sp[tid] - lse;
    if (tid < Hn){
      const float* row = ut + tid * Hn;
      float mm = -INFINITY;
      for (int j = 0; j < Hn; ++j) mm = fmaxf(mm, row[j]);
      float ss = 0.f;
      for (int j = 0; j < Hn; ++j) ss += __expf(row[j] - mm);
      float l = mm + __logf(ss);
      for (int j = 0; j < Hn; ++j){
        float v = row[j] - l;
        ws[OFF_LT + tid*Hn + j] = v;
        ws[OFF_PT + tid*Hn + j] = __expf(v);
      }
    }
    for (int r = tid; r < Sn*Hn; r += blockDim.x){
      const float* row = ue + (size_t)r * On;
      float mm = -INFINITY;
      for (int o = 0; o < On; ++o) mm = fmaxf(mm, row[o]);
      float ss = 0.f;
      for (int o = 0; o < On; ++o) ss += __expf(row[o] - mm);
      float inv = 1.f/ss;
      for (int o = 0; o < On; ++o) ws[OFF_EM + (size_t)r*On + o] = __expf(row[o]-mm)*inv;
    }
    return;
  }
  // ---- conv ----
  int i = blockIdx.x * blockDim.x + tid;
  const float* s2; unsigned short* d; int k;
  if (i < n4a){ s2 = srcA; d = dstA; k = i; }
  else { k = i - n4a; if (k >= n4b) return; s2 = srcB; d = dstB; }
  float4 v = ((const float4*)s2)[k];
  ushort4 r;
  r.x = f2bf(v.x); r.y = f2bf(v.y); r.z = f2bf(v.z); r.w = f2bf(v.w);
  ((ushort4*)d)[k] = r;
}

// ---------------- bf16 MFMA GEMM + fused softmax/mix/obs-dot epilogue ----------
// R13: TWO blocks per CU. Barrier-lockstep makes LDS-read and MFMA windows
// strictly alternate within a block (per-CU model: 2100cy LDS + 1860cy MFMA
// per K-tile, serialized = the 150us fixed point of R7/R11/R12). Two
// INDEPENDENT co-resident blocks overlap X's LDS window with Y's MFMA window
// (m114 mechanism). 128x192 tile, 4 waves (2x2, wave-tile 64x96), BK=64,
// full double buffer A 2x16K + B 2x24K = 81920 B exactly (2x81920 = 160KiB);
// bias/em live in the dead staging region during epilogue only. 4-phase
// kk/j-half split, single vmcnt(0) per tile. Slab swizzle kept (FETCH
// 110MB verified in R11/R12).
constexpr int BM = 128, BN = 192, BK = 64;
constexpr int NKT = Dn / BK;         // 12 K-tiles
// LDS byte map: A[2] @ 0 (2x16384), B[2] @ 32768 (2x24576), total 81920.

#define GEMM_BAR()  asm volatile("s_barrier" ::: "memory")
#define GEMM_LGKM() asm volatile("s_waitcnt lgkmcnt(0)" ::: "memory")

__global__ __launch_bounds__(256, 2) void gemm_lep_kernel(
    const unsigned short* __restrict__ embB, const unsigned short* __restrict__ WB,
    const float* __restrict__ bm, const float* __restrict__ obs,
    float* __restrict__ ws){
  __shared__ __align__(16) char smem[81920];   // staging; aliased by C-park+bias
  const int tid = threadIdx.x, lane = tid & 63, w = tid >> 6;   // w 0..3
  // XCD slab swizzle: 3072 blocks. XCD x owns m-quarter (x&3) x N-half (x>>2);
  // inner loop over m (16 m-tiles, A slab 3.1MB L2-resident), outer over n.
  const int bid = blockIdx.y * (Mn/BM) + blockIdx.x;
  const int xcd = bid & 7, j_loc = bid >> 3;     // j_loc in [0,384)
  const int xm = xcd & 3, xn = xcd >> 2;
  const int mloc = j_loc & 15, nloc = j_loc >> 4; // 16 m-tiles, 24 n-panels
  const int m0 = (xm*16 + mloc) * BM;             // m-tile 0..63
  const int by = xn*24 + nloc;                    // N-panel 0..47
  const int N0 = by * BN;
  const int wm = w & 1, wn = w >> 1;           // 2 x 2 wave grid
  const int lm = lane & 15, q = lane >> 4;
  const int key = lm & 7;
  const int srow = lane >> 3, spc = lane & 7;
  const int aoff0 = (q ^ key) << 4;            // kk=0 chunk byte offset
  const int aoff1 = ((4 + q) ^ key) << 4;      // kk=1

  f32x4 acc[4][6];
#pragma unroll
  for (int i = 0; i < 4; ++i)
#pragma unroll
    for (int j = 0; j < 6; ++j) acc[i][j] = (f32x4){0.f,0.f,0.f,0.f};

  auto stageA = [&](int kt, int i){            // i = 0..3 -> 128 rows
    const int idx = w*4 + i;                   // 0..15
    const int row = idx*8 + srow;
    const int lc  = spc ^ (row & 7);
    gload_lds16(embB + (size_t)(m0+row)*Dn + kt*BK + lc*8,
                smem + (kt & 1)*16384 + idx*1024);
  };
  auto stageB = [&](int kt, int i){            // i = 0..5 -> 192 rows
    const int idx = w*6 + i;                   // 0..23
    const int row = idx*8 + srow;
    const int lc  = spc ^ (row & 7);
    gload_lds16(WB + (size_t)(N0+row)*Dn + kt*BK + lc*8,
                smem + 32768 + (kt & 1)*24576 + idx*1024);
  };

  // prologue: stage K-tile 0 (10 loads), wait, barrier
#pragma unroll
  for (int i = 0; i < 4; ++i) stageA(0, i);
#pragma unroll
  for (int i = 0; i < 6; ++i) stageB(0, i);
  asm volatile("s_waitcnt vmcnt(0)" ::: "memory");
  GEMM_BAR();

  for (int kt = 0; kt < NKT; ++kt){
    const char* Ab = smem + (kt & 1)*16384;
    const char* Bb = smem + 32768 + (kt & 1)*24576;
    const int pf = kt + 1;
    const bool dopf = pf < NKT;
    short8 af[4], bf[3];

    // ---- P1: kk0, j0-2  (reads 3B + 4A; stage 4A+2B) ----
#pragma unroll
    for (int j = 0; j < 3; ++j)
      bf[j] = *(const short8*)(Bb + (wn*96 + j*16 + lm)*128 + aoff0);
#pragma unroll
    for (int i = 0; i < 4; ++i)
      af[i] = *(const short8*)(Ab + (wm*64 + i*16 + lm)*128 + aoff0);
    if (dopf){ stageA(pf,0); stageA(pf,1); stageA(pf,2); stageA(pf,3);
               stageB(pf,0); stageB(pf,1); }
    GEMM_BAR();
    GEMM_LGKM();
    __builtin_amdgcn_s_setprio(1);
#pragma unroll
    for (int i = 0; i < 4; ++i)
#pragma unroll
      for (int j = 0; j < 3; ++j)
        acc[i][j] = __builtin_amdgcn_mfma_f32_16x16x32_bf16(af[i], bf[j], acc[i][j], 0, 0, 0);
    __builtin_amdgcn_s_setprio(0);
    GEMM_BAR();

    // ---- P2: kk0, j3-5  (reads 3B; stage 2B) ----
#pragma unroll
    for (int j = 0; j < 3; ++j)
      bf[j] = *(const short8*)(Bb + (wn*96 + (3+j)*16 + lm)*128 + aoff0);
    if (dopf){ stageB(pf,2); stageB(pf,3); }
    GEMM_BAR();
    GEMM_LGKM();
    __builtin_amdgcn_s_setprio(1);
#pragma unroll
    for (int i = 0; i < 4; ++i)
#pragma unroll
      for (int j = 0; j < 3; ++j)
        acc[i][3+j] = __builtin_amdgcn_mfma_f32_16x16x32_bf16(af[i], bf[j], acc[i][3+j], 0, 0, 0);
    __builtin_amdgcn_s_setprio(0);
    GEMM_BAR();

    // ---- P3: kk1, j0-2  (reads 3B + 4A; stage 2B) ----
#pragma unroll
    for (int j = 0; j < 3; ++j)
      bf[j] = *(const short8*)(Bb + (wn*96 + j*16 + lm)*128 + aoff1);
#pragma unroll
    for (int i = 0; i < 4; ++i)
      af[i] = *(const short8*)(Ab + (wm*64 + i*16 + lm)*128 + aoff1);
    if (dopf){ stageB(pf,4); stageB(pf,5); }
    GEMM_BAR();
    GEMM_LGKM();
    __builtin_amdgcn_s_setprio(1);
#pragma unroll
    for (int i = 0; i < 4; ++i)
#pragma unroll
      for (int j = 0; j < 3; ++j)
        acc[i][j] = __builtin_amdgcn_mfma_f32_16x16x32_bf16(af[i], bf[j], acc[i][j], 0, 0, 0);
    __builtin_amdgcn_s_setprio(0);
    GEMM_BAR();

    // ---- P4: kk1, j3-5  (reads 3B; end-of-tile vmcnt(0)) ----
#pragma unroll
    for (int j = 0; j < 3; ++j)
      bf[j] = *(const short8*)(Bb + (wn*96 + (3+j)*16 + lm)*128 + aoff1);
    GEMM_BAR();
    GEMM_LGKM();
    __builtin_amdgcn_s_setprio(1);
#pragma unroll
    for (int i = 0; i < 4; ++i)
#pragma unroll
      for (int j = 0; j < 3; ++j)
        acc[i][3+j] = __builtin_amdgcn_mfma_f32_16x16x32_bf16(af[i], bf[j], acc[i][3+j], 0, 0, 0);
    __builtin_amdgcn_s_setprio(0);
    asm volatile("s_waitcnt vmcnt(0)" ::: "memory");   // tile kt+1 landed
    GEMM_BAR();
  }

  // ---- epilogue: park C (64 rows x stride 193) + bias/em tables over dead
  //      staging; fused softmax / mix / obs-dot / log. 2 halves of 64 rows;
  //      each half parked by the 2 waves owning it, computed by all 256
  //      threads (64 rows x 4 groups).
  float* Cp  = (float*)smem;
  float* ext = (float*)(smem + 49408);   // bias [0..191], em [192..383]
  if (tid < 192){
    ext[tid]       = bm[N0 + tid];
    ext[192 + tid] = ws[OFF_EM + N0 + tid];
  }
#pragma unroll
  for (int h = 0; h < 2; ++h){
    if (h) __syncthreads();
    if (wm == h){
#pragma unroll
      for (int i = 0; i < 4; ++i)
#pragma unroll
        for (int j = 0; j < 6; ++j){
          const int col = wn*96 + j*16 + lm;
#pragma unroll
          for (int r = 0; r < 4; ++r){
            const int rowl = i*16 + q*4 + r;
            Cp[rowl*193 + col] = acc[i][j][r];
          }
        }
    }
    __syncthreads();
    {
      const int rowl = tid >> 2, grp = tid & 3;
      const int m = m0 + h*64 + rowl;
      const int g = by*4 + grp;
      const int s2 = g / Hn;                   // constant per block
      const float* crow = Cp + rowl*193 + grp*48;
      const float* ob   = obs + ((size_t)m*Sn + s2)*On;
      const float* bi   = ext + grp*48;
      const float* em   = ext + 192 + grp*48;
      float Z = 0.f, pd = 0.f, eo = 0.f;
#pragma unroll
      for (int o = 0; o < On; ++o){
        float e = __expf(crow[o] + bi[o]);
        float obv = ob[o];
        Z += e;
        pd = fmaf(e, obv, pd);
        eo = fmaf(em[o], obv, eo);
      }
      ws[OFF_LEPP + (size_t)m*Gn + g] = __logf((1.f-EMISS_W)*eo + EMISS_W*(pd/Z));
    }
  }
}

// ---------------- forward/backward recursions: chunked with warm-up ----------
// Serial depth 40 (FBW warm-up + FBL chunk). Stages exp(sum of 4 lep
// partials) straight from OFF_LEPP (lep_reduce kernel deleted).
constexpr int FBW = 24;   // warm-up steps
constexpr int FBL = 16;   // chunk length

__global__ __launch_bounds__(64) void fb_kernel(float* __restrict__ ws){
  __shared__ __align__(16) float ldsE[(FBW+FBL)*48];   // exp(lep) window
  __shared__ __align__(16) float ring[2][64];
  const int lane = threadIdx.x;
  const int c    = blockIdx.x;
  const int b    = blockIdx.y;
  const bool fwd = blockIdx.z == 0;
  const bool act = lane < Hn;
  const int t0 = c*FBL, te = t0 + FBL - 1;

  float pt[Hn];
#pragma unroll
  for (int i = 0; i < Hn; ++i)
    pt[i] = act ? (fwd ? ws[OFF_PT + i*Hn + lane] : ws[OFF_PT + lane*Hn + i]) : 0.f;

  int row_lo, nrows, sA, sZ;
  bool exact;
  if (fwd){
    sA = t0 - FBW;
    exact = (sA < 1);
    row_lo = exact ? 0 : sA;
    if (exact) sA = 1;
    sZ = te;
    nrows = te - row_lo + 1;
  } else {
    int th = te + 1 + FBW;
    exact = (th > Tn - 2);
    sA = exact ? Tn - 2 : th - 1;
    sZ = t0;
    row_lo = t0;
    nrows = sA - t0 + 1;
  }

  // stage exp(lep) = exp(sum of 4 partials) from [m][192] layout
  {
    const float* src = ws + OFF_LEPP + ((size_t)b*Tn + row_lo)*Gn;
    int n4 = nrows * (Hn/4);
    for (int i = lane; i < n4; i += 64){
      int r = i / (Hn/4), h4 = i - r*(Hn/4);
      const float* p = src + (size_t)r*Gn + h4*4;
      float4 a = *(const float4*)(p);
      float4 b2 = *(const float4*)(p + Hn);
      float4 c2 = *(const float4*)(p + 2*Hn);
      float4 d2 = *(const float4*)(p + 3*Hn);
      float4 e;
      e.x = __expf(a.x + b2.x + c2.x + d2.x);
      e.y = __expf(a.y + b2.y + c2.y + d2.y);
      e.z = __expf(a.z + b2.z + c2.z + d2.z);
      e.w = __expf(a.w + b2.w + c2.w + d2.w);
      ((float4*)ldsE)[i] = e;
    }
  }
  __syncthreads();

  if (fwd){
    const size_t laF = OFF_LA + (size_t)b * Tn * Hn;
    float v;
    if (exact){
      v = act ? __expf(ws[OFF_LP + lane]) * ldsE[lane] : 0.f;   // alpha_0
      if (c == 0 && act) ws[laF + lane] = v;
    } else {
      v = act ? 1.f : 0.f;
    }
    if (act) ring[0][lane] = v;
    __syncthreads();
    int cur = 0;
    for (int t = sA; t <= sZ; ++t){
      float S = waveSum(v);
      const float* rp = ring[cur];
      float s0=0.f,s1=0.f,s2=0.f,s3=0.f;
#pragma unroll
      for (int i = 0; i < Hn; i += 4){
        float4 a = *(const float4*)(rp + i);
        s0 = fmaf(a.x, pt[i+0], s0); s1 = fmaf(a.y, pt[i+1], s1);
        s2 = fmaf(a.z, pt[i+2], s2); s3 = fmaf(a.w, pt[i+3], s3);
      }
      float sd = (s0+s1)+(s2+s3);
      float e = act ? ldsE[(t - row_lo)*Hn + lane] : 0.f;
      float vn = act ? e * sd * (1.f/S) : 0.f;
      cur ^= 1;
      if (act) ring[cur][lane] = vn;
      __syncthreads();
      if (act && t >= t0) ws[laF + (size_t)t*Hn + lane] = vn;
      v = vn;
    }
  } else {
    const size_t lbF = OFF_LB + (size_t)b * Tn * Hn;
    float v = act ? 1.f : 0.f;
    if (exact && c == (Tn/FBL - 1) && act) ws[lbF + (size_t)(Tn-1)*Hn + lane] = 1.f;
    int cur = 0;
    for (int t = sA; t >= sZ; --t){
      float e = act ? ldsE[(t - row_lo)*Hn + lane] : 0.f;
      float wv = e * v;
      if (act) ring[cur][lane] = wv;
      float S = waveSum(wv);
      __syncthreads();
      const float* rp = ring[cur];
      float s0=0.f,s1=0.f,s2=0.f,s3=0.f;
#pragma unroll
      for (int j = 0; j < Hn; j += 4){
        float4 a = *(const float4*)(rp + j);
        s0 = fmaf(a.x, pt[j+0], s0); s1 = fmaf(a.y, pt[j+1], s1);
        s2 = fmaf(a.z, pt[j+2], s2); s3 = fmaf(a.w, pt[j+3], s3);
      }
      float vn = act ? ((s0+s1)+(s2+s3)) * (1.f/S) : 0.f;
      cur ^= 1;
      if (act && t <= te) ws[lbF + (size_t)t*Hn + lane] = vn;
      v = vn;
    }
  }
}

// -------- gamma / xi / masked accumulation (prob domain, no atomics) -----------
// One coalesced partial store per block; sum_kernel reduces. (R9's last-block
// counter pattern = 8192 serialized same-address atomics+fences = 165us. Never
// funnel per-block completion through one address on this chip.)
__global__ __launch_bounds__(256) void gamma_xi_kernel(
    const float* __restrict__ ws_c, float* __restrict__ ws,
    const int* __restrict__ seq_len){
  __shared__ float y_s[Hn], lap_s[Hn];
  __shared__ float red[8];
  const int tid = threadIdx.x;
  const int bid = blockIdx.x;
  const int b = bid >> 9, t = bid & (Tn-1);
  const int len = seq_len[b];
  int tb = t + (Tn - len); if (tb >= Tn) tb -= Tn;
  const size_t bt = (size_t)b*Tn + t;
  float lep = 0.f;
  if (tid < Hn){
    const float* lpp = ws_c + OFF_LEPP + bt*Gn + tid;
    lep = lpp[0] + lpp[Hn] + lpp[2*Hn] + lpp[3*Hn];
    float lb  = ws_c[OFF_LB + ((size_t)b*Tn + tb)*Hn + tid];
    y_s[tid] = __expf(lep) * lb;
    if (t >= 1) lap_s[tid] = ws_c[OFF_LA + (bt-1)*Hn + tid];
  }
  float emis_term = 0.f, prior_term = 0.f;
  if (tid < 64){
    int h = (tid < Hn) ? tid : 0;
    float la  = ws_c[OFF_LA + bt*Hn + h];
    float lb  = ws_c[OFF_LB + ((size_t)b*Tn + tb)*Hn + h];
    float lp  = ws_c[OFF_LP + h];
    float wgt = (tid < Hn) ? la*lb : 0.f;
    float Z = waveSum(wgt);
    float inv = 1.f / Z;
    emis_term  = waveSum(wgt * lep) * inv;
    prior_term = waveSum(wgt * lp) * inv;
  }
  __syncthreads();
  float tran_term = 0.f;
  if (t >= 1){
    float se = 0.f, st = 0.f;
#pragma unroll
    for (int k=0;k<9;++k){
      int e = tid + k*256;
      int i = e / Hn, j = e - i*Hn;
      float e2 = ws_c[OFF_PT + e] * lap_s[i] * y_s[j];
      se += e2;
      st = fmaf(e2, ws_c[OFF_LT + e], st);
    }
    se = waveSum(se);
    st = waveSum(st);
    const int wid = tid >> 6;
    if ((tid & 63) == 0){ red[wid] = se; red[4+wid] = st; }
    __syncthreads();
    if (tid == 0){
      float SE = red[0]+red[1]+red[2]+red[3];
      float ST = red[4]+red[5]+red[6]+red[7];
      tran_term = ST / SE;
    }
  }
  if (tid == 0){
    float tot = 0.f;
    if (t < len)            tot += emis_term;
    if (t == 0)             tot += prior_term;
    if (t >= 1 && t < len)  tot += tran_term;
    ws[OFF_RED + bid] = tot;
  }
}

// ---------------- final reduction: 8192 partials -> scalar ---------------------
__global__ __launch_bounds__(256) void sum_kernel(const float* __restrict__ ws,
                                                  float* __restrict__ out){
  __shared__ float red[4];
  const int tid = threadIdx.x;
  float s = 0.f;
  for (int i = tid; i < Mn; i += 256) s += ws[OFF_RED + i];
  s = waveSum(s);
  if ((tid & 63) == 0) red[tid >> 6] = s;
  __syncthreads();
  if (tid == 0) out[0] = (red[0]+red[1]+red[2]+red[3]) * (1.f / Bn);
}

} // namespace

extern "C" void kernel_launch(void* const* d_in, const int* in_sizes, int n_in,
                              void* d_out, int out_size, void* d_ws, size_t ws_size,
                              hipStream_t stream){
  const float* emb = (const float*)d_in[0];
  const float* obs = (const float*)d_in[1];
  const float* sp  = (const float*)d_in[2];
  const float* ut  = (const float*)d_in[3];
  const float* ue  = (const float*)d_in[4];
  const float* Wm  = (const float*)d_in[5];
  const float* bm  = (const float*)d_in[6];
  const int*   sl  = (const int*)d_in[7];
  float* ws  = (float*)d_ws;
  float* out = (float*)d_out;
  (void)in_sizes; (void)n_in; (void)ws_size; (void)out_size;

  unsigned short* embB = (unsigned short*)(ws + FLOATS_END);
  unsigned short* WB   = embB + (size_t)Mn * Dn;

  const int n4a = Mn*Dn/4, n4b = Nn*Dn/4;
  const int nconv = (n4a + n4b + 255)/256;
  convprep_kernel<<<nconv + 1, 256, 0, stream>>>(emb, embB, n4a, Wm, WB, n4b,
                                                 sp, ut, ue, ws, nconv);
  gemm_lep_kernel<<<dim3(Mn/BM, Nn/BN), 256, 0, stream>>>(embB, WB, bm, obs, ws);
  fb_kernel<<<dim3(Tn/FBL, Bn, 2), 64, 0, stream>>>(ws);
  gamma_xi_kernel<<<Bn*Tn, 256, 0, stream>>>(ws, ws, sl);
  sum_kernel<<<1, 256, 0, stream>>>(ws, out);
}

// Round 5
// 288.662 us; speedup vs baseline: 1.0376x; 1.0201x over previous
//
#include <hip/hip_runtime.h>
#include <math.h>

namespace {

constexpr int Bn = 16, Tn = 512, Dn = 768, Sn = 4, Hn = 48, On = 48;
constexpr int Mn = Bn * Tn;          // 8192 (b,t) rows
constexpr int Gn = Sn * Hn;          // 192 (s,h) groups
constexpr int Nn = Gn * On;          // 9216 flat N (= flat W rows)
constexpr float EMISS_W = 0.5f;

// workspace layout (float offsets), then bf16 regions ~27 MB
constexpr size_t OFF_LP   = 0;
constexpr size_t OFF_LT   = 64;
constexpr size_t OFF_PT   = OFF_LT + Hn*Hn;
constexpr size_t OFF_EM   = OFF_PT + Hn*Hn;
constexpr size_t OFF_LEPP = OFF_EM + (size_t)Sn*Hn*On;   // [m][g] g = s*48+h (log partials)
constexpr size_t OFF_LA   = OFF_LEPP + (size_t)Mn*Gn;    // alpha probs (per-t scale)
constexpr size_t OFF_LB   = OFF_LA + (size_t)Mn*Hn;      // beta probs (per-t scale)
constexpr size_t OFF_RED  = OFF_LB + (size_t)Mn*Hn;      // per-(b,t) partials [8192]
constexpr size_t FLOATS_END = OFF_RED + (size_t)Mn;

typedef __attribute__((ext_vector_type(8))) short short8;
typedef __attribute__((ext_vector_type(4))) float f32x4;

__device__ inline float waveSum(float v){
#pragma unroll
  for (int o = 32; o; o >>= 1) v += __shfl_xor(v, o);
  return v;
}

__device__ inline unsigned short f2bf(float f){
  unsigned int u = __float_as_uint(f);
  u += 0x7FFFu + ((u >> 16) & 1u);   // round-to-nearest-even
  return (unsigned short)(u >> 16);
}

__device__ inline void gload_lds16(const void* g, void* l){
  __builtin_amdgcn_global_load_lds(
      (const __attribute__((address_space(1))) void*)g,
      (__attribute__((address_space(3))) void*)l, 16, 0, 0);
}

// -------- conversion (all blocks but last) + param preprocessing (last block) --
__global__ void convprep_kernel(const float* __restrict__ srcA, unsigned short* __restrict__ dstA,
                                int n4a,
                                const float* __restrict__ srcB, unsigned short* __restrict__ dstB,
                                int n4b,
                                const float* __restrict__ sp, const float* __restrict__ ut,
                                const float* __restrict__ ue, float* __restrict__ ws,
                                int nconv){
  const int tid = threadIdx.x;
  if ((int)blockIdx.x == nconv){
    // ---- prep ----
    float m = -INFINITY;
    for (int h = 0; h < Hn; ++h) m = fmaxf(m, sp[h]);
    float s = 0.f;
    for (int h = 0; h < Hn; ++h) s += __expf(sp[h] - m);
    float lse = m + __logf(s);
    if (tid < Hn) ws[OFF_LP + tid] = sp[tid] - lse;
    if (tid < Hn){
      const float* row = ut + tid * Hn;
      float mm = -INFINITY;
      for (int j = 0; j < Hn; ++j) mm = fmaxf(mm, row[j]);
      float ss = 0.f;
      for (int j = 0; j < Hn; ++j) ss += __expf(row[j] - mm);
      float l = mm + __logf(ss);
      for (int j = 0; j < Hn; ++j){
        float v = row[j] - l;
        ws[OFF_LT + tid*Hn + j] = v;
        ws[OFF_PT + tid*Hn + j] = __expf(v);
      }
    }
    for (int r = tid; r < Sn*Hn; r += blockDim.x){
      const float* row = ue + (size_t)r * On;
      float mm = -INFINITY;
      for (int o = 0; o < On; ++o) mm = fmaxf(mm, row[o]);
      float ss = 0.f;
      for (int o = 0; o < On; ++o) ss += __expf(row[o] - mm);
      float inv = 1.f/ss;
      for (int o = 0; o < On; ++o) ws[OFF_EM + (size_t)r*On + o] = __expf(row[o]-mm)*inv;
    }
    return;
  }
  // ---- conv ----
  int i = blockIdx.x * blockDim.x + tid;
  const float* s2; unsigned short* d; int k;
  if (i < n4a){ s2 = srcA; d = dstA; k = i; }
  else { k = i - n4a; if (k >= n4b) return; s2 = srcB; d = dstB; }
  float4 v = ((const float4*)s2)[k];
  ushort4 r;
  r.x = f2bf(v.x); r.y = f2bf(v.y); r.z = f2bf(v.z); r.w = f2bf(v.w);
  ((ushort4*)d)[k] = r;
}

// ---------------- bf16 MFMA GEMM + fused softmax/mix/obs-dot epilogue ----------
// R14: de-phased schedule. R13's counters (MfmaUtil 37.5 with 2 blocks/CU)
// showed zero cross-wave overlap: 8 barriers + 4 lgkmcnt(0) full drains per
// K-tile kept all 8 waves/CU in lockstep, phase-locked on the shared LDS
// port. R14: per K-tile exactly ONE vmcnt(0)+s_barrier gate (1-deep prefetch
// into the opposite buffer; issue-to-wait distance ~1 full tile over
// L2-resident slabs), then 20 ds_read_b128 in cluster order, 10 stages for
// t+1, 4 MFMA clusters with COMPILER-counted lgkmcnt (m97-verified: hipcc
// emits precise lgkmcnt(N) from FIFO order). No other sync -> waves drift
// into complementary phases; block X's LDS window overlaps block Y's MFMA
// window (m114). Race-safe: tile-t reads buf t&1, stages write buf (t+1)&1;
// t-1's reads of that buffer drained (FIFO) before the tile-t barrier.
// 128x192 tile, 4 waves (2x2), BK=64, LDS 81920 B (2 blocks/CU), slab
// swizzle kept (FETCH 110-113MB verified R11-R13).
constexpr int BM = 128, BN = 192, BK = 64;
constexpr int NKT = Dn / BK;         // 12 K-tiles
// LDS byte map: A[2] @ 0 (2x16384), B[2] @ 32768 (2x24576), total 81920.

__global__ __launch_bounds__(256, 2) void gemm_lep_kernel(
    const unsigned short* __restrict__ embB, const unsigned short* __restrict__ WB,
    const float* __restrict__ bm, const float* __restrict__ obs,
    float* __restrict__ ws){
  __shared__ __align__(16) char smem[81920];   // staging; aliased by C-park+bias
  const int tid = threadIdx.x, lane = tid & 63, w = tid >> 6;   // w 0..3
  // XCD slab swizzle: 3072 blocks. XCD x owns m-quarter (x&3) x N-half (x>>2);
  // inner loop over m (16 m-tiles, A slab 3.1MB L2-resident), outer over n.
  const int bid = blockIdx.y * (Mn/BM) + blockIdx.x;
  const int xcd = bid & 7, j_loc = bid >> 3;     // j_loc in [0,384)
  const int xm = xcd & 3, xn = xcd >> 2;
  const int mloc = j_loc & 15, nloc = j_loc >> 4; // 16 m-tiles, 24 n-panels
  const int m0 = (xm*16 + mloc) * BM;             // m-tile 0..63
  const int by = xn*24 + nloc;                    // N-panel 0..47
  const int N0 = by * BN;
  const int wm = w & 1, wn = w >> 1;           // 2 x 2 wave grid
  const int lm = lane & 15, q = lane >> 4;
  const int key = lm & 7;
  const int srow = lane >> 3, spc = lane & 7;
  const int aoff0 = (q ^ key) << 4;            // kk=0 chunk byte offset
  const int aoff1 = ((4 + q) ^ key) << 4;      // kk=1

  f32x4 acc[4][6];
#pragma unroll
  for (int i = 0; i < 4; ++i)
#pragma unroll
    for (int j = 0; j < 6; ++j) acc[i][j] = (f32x4){0.f,0.f,0.f,0.f};

  auto stageA = [&](int kt, int i){            // i = 0..3 -> 128 rows
    const int idx = w*4 + i;                   // 0..15
    const int row = idx*8 + srow;
    const int lc  = spc ^ (row & 7);
    gload_lds16(embB + (size_t)(m0+row)*Dn + kt*BK + lc*8,
                smem + (kt & 1)*16384 + idx*1024);
  };
  auto stageB = [&](int kt, int i){            // i = 0..5 -> 192 rows
    const int idx = w*6 + i;                   // 0..23
    const int row = idx*8 + srow;
    const int lc  = spc ^ (row & 7);
    gload_lds16(WB + (size_t)(N0+row)*Dn + kt*BK + lc*8,
                smem + 32768 + (kt & 1)*24576 + idx*1024);
  };

  // prologue: stage K-tile 0 (10 loads); the in-loop gate handles the wait
#pragma unroll
  for (int i = 0; i < 4; ++i) stageA(0, i);
#pragma unroll
  for (int i = 0; i < 6; ++i) stageB(0, i);

  for (int kt = 0; kt < NKT; ++kt){
    const char* Ab = smem + (kt & 1)*16384;
    const char* Bb = smem + 32768 + (kt & 1)*24576;

    // ---- single gate per tile: own stages landed, all waves past prev tile
    asm volatile("s_waitcnt vmcnt(0)" ::: "memory");
    asm volatile("s_barrier" ::: "memory");

    // ---- 20 ds_read_b128 in cluster-consumption order (FIFO -> compiler
    //      emits counted lgkmcnt before each cluster, no manual waits)
    short8 a0[4], a1[4], b0[3], b1[3], b2[3], b3[3];
#pragma unroll
    for (int j = 0; j < 3; ++j)
      b0[j] = *(const short8*)(Bb + (wn*96 + j*16 + lm)*128 + aoff0);
#pragma unroll
    for (int i = 0; i < 4; ++i)
      a0[i] = *(const short8*)(Ab + (wm*64 + i*16 + lm)*128 + aoff0);
#pragma unroll
    for (int j = 0; j < 3; ++j)
      b1[j] = *(const short8*)(Bb + (wn*96 + (3+j)*16 + lm)*128 + aoff0);
#pragma unroll
    for (int i = 0; i < 4; ++i)
      a1[i] = *(const short8*)(Ab + (wm*64 + i*16 + lm)*128 + aoff1);
#pragma unroll
    for (int j = 0; j < 3; ++j)
      b2[j] = *(const short8*)(Bb + (wn*96 + j*16 + lm)*128 + aoff1);
#pragma unroll
    for (int j = 0; j < 3; ++j)
      b3[j] = *(const short8*)(Bb + (wn*96 + (3+j)*16 + lm)*128 + aoff1);

    // ---- stage next tile into the opposite buffer (no race with reads)
    const int pf = kt + 1;
    if (pf < NKT){
#pragma unroll
      for (int i = 0; i < 4; ++i) stageA(pf, i);
#pragma unroll
      for (int i = 0; i < 6; ++i) stageB(pf, i);
    }

    // ---- 4 MFMA clusters; compiler inserts lgkmcnt(13/10/3/0)
    __builtin_amdgcn_s_setprio(1);
#pragma unroll
    for (int i = 0; i < 4; ++i)
#pragma unroll
      for (int j = 0; j < 3; ++j)
        acc[i][j] = __builtin_amdgcn_mfma_f32_16x16x32_bf16(a0[i], b0[j], acc[i][j], 0, 0, 0);
#pragma unroll
    for (int i = 0; i < 4; ++i)
#pragma unroll
      for (int j = 0; j < 3; ++j)
        acc[i][3+j] = __builtin_amdgcn_mfma_f32_16x16x32_bf16(a0[i], b1[j], acc[i][3+j], 0, 0, 0);
#pragma unroll
    for (int i = 0; i < 4; ++i)
#pragma unroll
      for (int j = 0; j < 3; ++j)
        acc[i][j] = __builtin_amdgcn_mfma_f32_16x16x32_bf16(a1[i], b2[j], acc[i][j], 0, 0, 0);
#pragma unroll
    for (int i = 0; i < 4; ++i)
#pragma unroll
      for (int j = 0; j < 3; ++j)
        acc[i][3+j] = __builtin_amdgcn_mfma_f32_16x16x32_bf16(a1[i], b3[j], acc[i][3+j], 0, 0, 0);
    __builtin_amdgcn_s_setprio(0);
  }

  // ---- epilogue: park C (64 rows x stride 193) + bias/em tables over dead
  //      staging; fused softmax / mix / obs-dot / log. 2 halves of 64 rows;
  //      each half parked by the 2 waves owning it, computed by all 256
  //      threads (64 rows x 4 groups).
  __syncthreads();   // all waves done reading smem before C-park overwrites
  float* Cp  = (float*)smem;
  float* ext = (float*)(smem + 49408);   // bias [0..191], em [192..383]
  if (tid < 192){
    ext[tid]       = bm[N0 + tid];
    ext[192 + tid] = ws[OFF_EM + N0 + tid];
  }
#pragma unroll
  for (int h = 0; h < 2; ++h){
    if (h) __syncthreads();
    if (wm == h){
#pragma unroll
      for (int i = 0; i < 4; ++i)
#pragma unroll
        for (int j = 0; j < 6; ++j){
          const int col = wn*96 + j*16 + lm;
#pragma unroll
          for (int r = 0; r < 4; ++r){
            const int rowl = i*16 + q*4 + r;
            Cp[rowl*193 + col] = acc[i][j][r];
          }
        }
    }
    __syncthreads();
    {
      const int rowl = tid >> 2, grp = tid & 3;
      const int m = m0 + h*64 + rowl;
      const int g = by*4 + grp;
      const int s2 = g / Hn;                   // constant per block
      const float* crow = Cp + rowl*193 + grp*48;
      const float* ob   = obs + ((size_t)m*Sn + s2)*On;
      const float* bi   = ext + grp*48;
      const float* em   = ext + 192 + grp*48;
      float Z = 0.f, pd = 0.f, eo = 0.f;
#pragma unroll
      for (int o = 0; o < On; ++o){
        float e = __expf(crow[o] + bi[o]);
        float obv = ob[o];
        Z += e;
        pd = fmaf(e, obv, pd);
        eo = fmaf(em[o], obv, eo);
      }
      ws[OFF_LEPP + (size_t)m*Gn + g] = __logf((1.f-EMISS_W)*eo + EMISS_W*(pd/Z));
    }
  }
}

// ---------------- forward/backward recursions: chunked with warm-up ----------
// Serial depth 40 (FBW warm-up + FBL chunk). Stages exp(sum of 4 lep
// partials) straight from OFF_LEPP (lep_reduce kernel deleted).
constexpr int FBW = 24;   // warm-up steps
constexpr int FBL = 16;   // chunk length

__global__ __launch_bounds__(64) void fb_kernel(float* __restrict__ ws){
  __shared__ __align__(16) float ldsE[(FBW+FBL)*48];   // exp(lep) window
  __shared__ __align__(16) float ring[2][64];
  const int lane = threadIdx.x;
  const int c    = blockIdx.x;
  const int b    = blockIdx.y;
  const bool fwd = blockIdx.z == 0;
  const bool act = lane < Hn;
  const int t0 = c*FBL, te = t0 + FBL - 1;

  float pt[Hn];
#pragma unroll
  for (int i = 0; i < Hn; ++i)
    pt[i] = act ? (fwd ? ws[OFF_PT + i*Hn + lane] : ws[OFF_PT + lane*Hn + i]) : 0.f;

  int row_lo, nrows, sA, sZ;
  bool exact;
  if (fwd){
    sA = t0 - FBW;
    exact = (sA < 1);
    row_lo = exact ? 0 : sA;
    if (exact) sA = 1;
    sZ = te;
    nrows = te - row_lo + 1;
  } else {
    int th = te + 1 + FBW;
    exact = (th > Tn - 2);
    sA = exact ? Tn - 2 : th - 1;
    sZ = t0;
    row_lo = t0;
    nrows = sA - t0 + 1;
  }

  // stage exp(lep) = exp(sum of 4 partials) from [m][192] layout
  {
    const float* src = ws + OFF_LEPP + ((size_t)b*Tn + row_lo)*Gn;
    int n4 = nrows * (Hn/4);
    for (int i = lane; i < n4; i += 64){
      int r = i / (Hn/4), h4 = i - r*(Hn/4);
      const float* p = src + (size_t)r*Gn + h4*4;
      float4 a = *(const float4*)(p);
      float4 b2 = *(const float4*)(p + Hn);
      float4 c2 = *(const float4*)(p + 2*Hn);
      float4 d2 = *(const float4*)(p + 3*Hn);
      float4 e;
      e.x = __expf(a.x + b2.x + c2.x + d2.x);
      e.y = __expf(a.y + b2.y + c2.y + d2.y);
      e.z = __expf(a.z + b2.z + c2.z + d2.z);
      e.w = __expf(a.w + b2.w + c2.w + d2.w);
      ((float4*)ldsE)[i] = e;
    }
  }
  __syncthreads();

  if (fwd){
    const size_t laF = OFF_LA + (size_t)b * Tn * Hn;
    float v;
    if (exact){
      v = act ? __expf(ws[OFF_LP + lane]) * ldsE[lane] : 0.f;   // alpha_0
      if (c == 0 && act) ws[laF + lane] = v;
    } else {
      v = act ? 1.f : 0.f;
    }
    if (act) ring[0][lane] = v;
    __syncthreads();
    int cur = 0;
    for (int t = sA; t <= sZ; ++t){
      float S = waveSum(v);
      const float* rp = ring[cur];
      float s0=0.f,s1=0.f,s2=0.f,s3=0.f;
#pragma unroll
      for (int i = 0; i < Hn; i += 4){
        float4 a = *(const float4*)(rp + i);
        s0 = fmaf(a.x, pt[i+0], s0); s1 = fmaf(a.y, pt[i+1], s1);
        s2 = fmaf(a.z, pt[i+2], s2); s3 = fmaf(a.w, pt[i+3], s3);
      }
      float sd = (s0+s1)+(s2+s3);
      float e = act ? ldsE[(t - row_lo)*Hn + lane] : 0.f;
      float vn = act ? e * sd * (1.f/S) : 0.f;
      cur ^= 1;
      if (act) ring[cur][lane] = vn;
      __syncthreads();
      if (act && t >= t0) ws[laF + (size_t)t*Hn + lane] = vn;
      v = vn;
    }
  } else {
    const size_t lbF = OFF_LB + (size_t)b * Tn * Hn;
    float v = act ? 1.f : 0.f;
    if (exact && c == (Tn/FBL - 1) && act) ws[lbF + (size_t)(Tn-1)*Hn + lane] = 1.f;
    int cur = 0;
    for (int t = sA; t >= sZ; --t){
      float e = act ? ldsE[(t - row_lo)*Hn + lane] : 0.f;
      float wv = e * v;
      if (act) ring[cur][lane] = wv;
      float S = waveSum(wv);
      __syncthreads();
      const float* rp = ring[cur];
      float s0=0.f,s1=0.f,s2=0.f,s3=0.f;
#pragma unroll
      for (int j = 0; j < Hn; j += 4){
        float4 a = *(const float4*)(rp + j);
        s0 = fmaf(a.x, pt[j+0], s0); s1 = fmaf(a.y, pt[j+1], s1);
        s2 = fmaf(a.z, pt[j+2], s2); s3 = fmaf(a.w, pt[j+3], s3);
      }
      float vn = act ? ((s0+s1)+(s2+s3)) * (1.f/S) : 0.f;
      cur ^= 1;
      if (act && t <= te) ws[lbF + (size_t)t*Hn + lane] = vn;
      v = vn;
    }
  }
}

// -------- gamma / xi / masked accumulation (prob domain, no atomics) -----------
// One coalesced partial store per block; sum_kernel reduces. (R9's last-block
// counter pattern = 8192 serialized same-address atomics+fences = 165us. Never
// funnel per-block completion through one address on this chip.)
__global__ __launch_bounds__(256) void gamma_xi_kernel(
    const float* __restrict__ ws_c, float* __restrict__ ws,
    const int* __restrict__ seq_len){
  __shared__ float y_s[Hn], lap_s[Hn];
  __shared__ float red[8];
  const int tid = threadIdx.x;
  const int bid = blockIdx.x;
  const int b = bid >> 9, t = bid & (Tn-1);
  const int len = seq_len[b];
  int tb = t + (Tn - len); if (tb >= Tn) tb -= Tn;
  const size_t bt = (size_t)b*Tn + t;
  float lep = 0.f;
  if (tid < Hn){
    const float* lpp = ws_c + OFF_LEPP + bt*Gn + tid;
    lep = lpp[0] + lpp[Hn] + lpp[2*Hn] + lpp[3*Hn];
    float lb  = ws_c[OFF_LB + ((size_t)b*Tn + tb)*Hn + tid];
    y_s[tid] = __expf(lep) * lb;
    if (t >= 1) lap_s[tid] = ws_c[OFF_LA + (bt-1)*Hn + tid];
  }
  float emis_term = 0.f, prior_term = 0.f;
  if (tid < 64){
    int h = (tid < Hn) ? tid : 0;
    float la  = ws_c[OFF_LA + bt*Hn + h];
    float lb  = ws_c[OFF_LB + ((size_t)b*Tn + tb)*Hn + h];
    float lp  = ws_c[OFF_LP + h];
    float wgt = (tid < Hn) ? la*lb : 0.f;
    float Z = waveSum(wgt);
    float inv = 1.f / Z;
    emis_term  = waveSum(wgt * lep) * inv;
    prior_term = waveSum(wgt * lp) * inv;
  }
  __syncthreads();
  float tran_term = 0.f;
  if (t >= 1){
    float se = 0.f, st = 0.f;
#pragma unroll
    for (int k=0;k<9;++k){
      int e = tid + k*256;
      int i = e / Hn, j = e - i*Hn;
      float e2 = ws_c[OFF_PT + e] * lap_s[i] * y_s[j];
      se += e2;
      st = fmaf(e2, ws_c[OFF_LT + e], st);
    }
    se = waveSum(se);
    st = waveSum(st);
    const int wid = tid >> 6;
    if ((tid & 63) == 0){ red[wid] = se; red[4+wid] = st; }
    __syncthreads();
    if (tid == 0){
      float SE = red[0]+red[1]+red[2]+red[3];
      float ST = red[4]+red[5]+red[6]+red[7];
      tran_term = ST / SE;
    }
  }
  if (tid == 0){
    float tot = 0.f;
    if (t < len)            tot += emis_term;
    if (t == 0)             tot += prior_term;
    if (t >= 1 && t < len)  tot += tran_term;
    ws[OFF_RED + bid] = tot;
  }
}

// ---------------- final reduction: 8192 partials -> scalar ---------------------
__global__ __launch_bounds__(256) void sum_kernel(const float* __restrict__ ws,
                                                  float* __restrict__ out){
  __shared__ float red[4];
  const int tid = threadIdx.x;
  float s = 0.f;
  for (int i = tid; i < Mn; i += 256) s += ws[OFF_RED + i];
  s = waveSum(s);
  if ((tid & 63) == 0) red[tid >> 6] = s;
  __syncthreads();
  if (tid == 0) out[0] = (red[0]+red[1]+red[2]+red[3]) * (1.f / Bn);
}

} // namespace

extern "C" void kernel_launch(void* const* d_in, const int* in_sizes, int n_in,
                              void* d_out, int out_size, void* d_ws, size_t ws_size,
                              hipStream_t stream){
  const float* emb = (const float*)d_in[0];
  const float* obs = (const float*)d_in[1];
  const float* sp  = (const float*)d_in[2];
  const float* ut  = (const float*)d_in[3];
  const float* ue  = (const float*)d_in[4];
  const float* Wm  = (const float*)d_in[5];
  const float* bm  = (const float*)d_in[6];
  const int*   sl  = (const int*)d_in[7];
  float* ws  = (float*)d_ws;
  float* out = (float*)d_out;
  (void)in_sizes; (void)n_in; (void)ws_size; (void)out_size;

  unsigned short* embB = (unsigned short*)(ws + FLOATS_END);
  unsigned short* WB   = embB + (size_t)Mn * Dn;

  const int n4a = Mn*Dn/4, n4b = Nn*Dn/4;
  const int nconv = (n4a + n4b + 255)/256;
  convprep_kernel<<<nconv + 1, 256, 0, stream>>>(emb, embB, n4a, Wm, WB, n4b,
                                                 sp, ut, ue, ws, nconv);
  gemm_lep_kernel<<<dim3(Mn/BM, Nn/BN), 256, 0, stream>>>(embB, WB, bm, obs, ws);
  fb_kernel<<<dim3(Tn/FBL, Bn, 2), 64, 0, stream>>>(ws);
  gamma_xi_kernel<<<Bn*Tn, 256, 0, stream>>>(ws, ws, sl);
  sum_kernel<<<1, 256, 0, stream>>>(ws, out);
}